// Round 6
// baseline (145.656 us; speedup 1.0000x reference)
//
#include <hip/hip_runtime.h>
#include <hip/hip_bf16.h>

typedef __attribute__((ext_vector_type(8))) short bf16x8;
typedef __attribute__((ext_vector_type(4))) float f32x4;

#define NB 32
#define NS 512
#define ND 1024

__device__ __forceinline__ unsigned short f2bf(float f) {
  unsigned int u = __float_as_uint(f);
  u = (u + 0x7FFFu + ((u >> 16) & 1u)) >> 16;  // RNE
  return (unsigned short)u;
}

// ---------- normalized embeddings -> bf16; blocks 0..31 also do aspect ----------
__global__ __launch_bounds__(256)
void enormbf_fused_kernel(const float* __restrict__ emb,
                          unsigned short* __restrict__ eN,
                          const float* __restrict__ aspect,
                          unsigned short* __restrict__ a_n) {
  int wave = threadIdx.x >> 6, lane = threadIdx.x & 63;
  size_t row = (size_t)blockIdx.x * 4 + wave;  // 0..16383
  const float4* p = (const float4*)(emb + row * ND);
  float4 v[4];
  float s = 0.f;
#pragma unroll
  for (int j = 0; j < 4; ++j) {
    v[j] = p[lane + 64 * j];
    s += v[j].x * v[j].x + v[j].y * v[j].y + v[j].z * v[j].z + v[j].w * v[j].w;
  }
#pragma unroll
  for (int off = 32; off >= 1; off >>= 1) s += __shfl_xor(s, off);
  float inv = (s > 0.f) ? (1.f / sqrtf(s)) : 0.f;
  ushort4* o = (ushort4*)(eN + row * ND);
#pragma unroll
  for (int j = 0; j < 4; ++j) {
    ushort4 u;
    u.x = f2bf(v[j].x * inv); u.y = f2bf(v[j].y * inv);
    u.z = f2bf(v[j].z * inv); u.w = f2bf(v[j].w * inv);
    o[lane + 64 * j] = u;
  }

  if (blockIdx.x < NB) {  // fused anorm for batch b = blockIdx.x
    int b = blockIdx.x;
    int t = threadIdx.x;
    const float4* pa = (const float4*)(aspect + (size_t)b * ND);
    float4 va = pa[t];
    float sa = va.x * va.x + va.y * va.y + va.z * va.z + va.w * va.w;
#pragma unroll
    for (int off = 32; off >= 1; off >>= 1) sa += __shfl_down(sa, off);
    __shared__ float red[4];
    if ((t & 63) == 0) red[t >> 6] = sa;
    __syncthreads();
    float tot = red[0] + red[1] + red[2] + red[3];
    float inva = (tot > 0.f) ? (1.f / sqrtf(tot)) : 0.f;
    ushort4 u;
    u.x = f2bf(va.x * inva); u.y = f2bf(va.y * inva);
    u.z = f2bf(va.z * inva); u.w = f2bf(va.w * inva);
    ((ushort4*)(a_n + (size_t)b * ND))[t] = u;
  }
}

// ---------- GEMM v9: 64x256 tile, 4 waves (1m x 4n), wave-tile 64x64,
// ring-2 A via global_load_lds, 37 KB LDS -> 4 blocks/CU = 16 waves/CU
// (4/SIMD). All 1024 blocks co-resident. 2 counted-lgkm phases + 1 barrier
// per K-tile; stage issued at tile start so the seam vmcnt(0) is cheap.
// Theory: 4 waves/SIMD absorb LDS queueing that capped 2-wave/SIMD at ~30%.
__global__ __launch_bounds__(256)
void corr_gemm9_kernel(const unsigned short* __restrict__ eN,
                       const unsigned short* __restrict__ a_n,
                       float* __restrict__ out) {
  __shared__ __align__(16) unsigned short Alds[2 * 4096];    // 2 x 64 x 64
  __shared__ __align__(16) unsigned short copies[8 * 1288];  // circulant window

  const int b = blockIdx.x, mt = blockIdx.y, nt = blockIdx.z;
  const int n0 = nt * 256, m0 = mt * 64;
  const int tid = threadIdx.x;

  const int lane = tid & 63, wn = tid >> 6;  // 4 waves = 4 col-quarters (64x64 each)
  const int q = lane >> 4, l16 = lane & 15;
  const int mx = l16 & 7;
  const int s00 = (q ^ mx) * 8;              // chunk q     (kk=0)
  const int s01 = ((4 + q) ^ mx) * 8;        // chunk 4+q   (kk=1)
  const int arow = l16 * 64;

  // B read: addr = copies + pB*1287 + idx; idx = kt*64 + kk*32 + 8q + 256 - n_local
  const int pB = (8 - mx) & 7;
  const unsigned short* Bp = copies + pB * 1287 + (256 + 8 * q - wn * 64 - l16);

  // A staging source (inverse chunk swizzle); LDS dst = slot + tid*16 + j*4096
  const unsigned short* gstage =
      eN + ((size_t)b * NS + m0 + (tid >> 3)) * ND + (size_t)(((tid & 7) ^ ((tid >> 3) & 7)) * 8);
  char* ldsAbase = (char*)Alds;

  // ---- prologue 1: gather a_n window into regs (oldest vmem) ----
  unsigned short av[40];
  {
    const unsigned short* an = a_n + (size_t)b * ND;
    const int p = tid & 7;
    const int x0 = (tid >> 3) * 40;  // 32 threads/copy x 40 = 1280
    const int base = (768 - n0 + p) & 1023;
#pragma unroll
    for (int j = 0; j < 40; ++j) av[j] = an[(base + x0 + j) & 1023];
  }

  // ---- prologue 2: stage tile 0 into slot 0 (2 gloads, stay in flight) ----
#pragma unroll
  for (int j = 0; j < 2; ++j)
    __builtin_amdgcn_global_load_lds(
        (const __attribute__((address_space(1))) void*)(gstage + (size_t)j * 32 * ND),
        (__attribute__((address_space(3))) void*)(ldsAbase + (size_t)tid * 16 + j * 4096),
        16, 0, 0);

  // ---- prologue 3: write copies (compiler drains av-loads, keeps stages) ----
  {
    const int p = tid & 7;
    const int x0 = (tid >> 3) * 40;
#pragma unroll
    for (int j = 0; j < 40; ++j) copies[p * 1288 + x0 + j] = av[j];
  }

  f32x4 acc[4][4];
#pragma unroll
  for (int i = 0; i < 4; ++i)
#pragma unroll
    for (int j = 0; j < 4; ++j)
      acc[i][j] = (f32x4){0.f, 0.f, 0.f, 0.f};

  asm volatile("s_waitcnt lgkmcnt(0)" ::: "memory");  // copies ds_writes done
  __builtin_amdgcn_sched_barrier(0);
  __builtin_amdgcn_s_barrier();                       // copies visible block-wide
  asm volatile("s_waitcnt vmcnt(0)" ::: "memory");    // slot0 staged
  __builtin_amdgcn_sched_barrier(0);
  __builtin_amdgcn_s_barrier();                       // slot0 ready for all waves

  bf16x8 a0[4], a1[4], b0[4], b1[4];

#define STAGE2(SLOT, KTT)                                                              \
  do {                                                                                 \
    const unsigned short* sg_ = gstage + (size_t)(KTT) * 64;                           \
    char* dl_ = ldsAbase + (SLOT) * 8192 + (size_t)tid * 16;                           \
    _Pragma("unroll")                                                                  \
    for (int j = 0; j < 2; ++j)                                                        \
      __builtin_amdgcn_global_load_lds(                                                \
          (const __attribute__((address_space(1))) void*)(sg_ + (size_t)j * 32 * ND),  \
          (__attribute__((address_space(3))) void*)(dl_ + j * 4096), 16, 0, 0);        \
  } while (0)

#define MFMA16(AR, BR)                                                                 \
  do {                                                                                 \
    __builtin_amdgcn_s_setprio(1);                                                     \
    _Pragma("unroll")                                                                  \
    for (int n = 0; n < 4; ++n) {                                                      \
      _Pragma("unroll")                                                                \
      for (int r = 0; r < 4; ++r)                                                      \
        acc[r][n] = __builtin_amdgcn_mfma_f32_16x16x32_bf16(AR[r], BR[n], acc[r][n], 0, 0, 0); \
    }                                                                                  \
    __builtin_amdgcn_s_setprio(0);                                                     \
  } while (0)

#pragma unroll 1
  for (int kt = 0; kt < 16; ++kt) {
    const unsigned short* At = Alds + (kt & 1) * 4096;

    if (kt < 15) STAGE2((kt & 1) ^ 1, kt + 1);  // vmem issue at tile start

    // issue kk0 operands (8 ds_read), then kk1 (8 more) -> 16 outstanding
    const unsigned short* Bt = Bp + kt * 64;
#pragma unroll
    for (int r = 0; r < 4; ++r) a0[r] = *(const bf16x8*)&At[arow + r * 1024 + s00];
#pragma unroll
    for (int n = 0; n < 4; ++n) b0[n] = *(const bf16x8*)(Bt - n * 16);
#pragma unroll
    for (int r = 0; r < 4; ++r) a1[r] = *(const bf16x8*)&At[arow + r * 1024 + s01];
#pragma unroll
    for (int n = 0; n < 4; ++n) b1[n] = *(const bf16x8*)(Bt + 32 - n * 16);

    asm volatile("s_waitcnt lgkmcnt(8)" ::: "memory");  // kk0 ready; kk1 in flight
    __builtin_amdgcn_sched_barrier(0);
    MFMA16(a0, b0);

    asm volatile("s_waitcnt lgkmcnt(0)" ::: "memory");  // kk1 ready
    __builtin_amdgcn_sched_barrier(0);
    MFMA16(a1, b1);

    // tile seam: next slot fully staged (loads issued a full tile ago -> cheap)
    asm volatile("s_waitcnt vmcnt(0)" ::: "memory");
    __builtin_amdgcn_sched_barrier(0);
    __builtin_amdgcn_s_barrier();  // all waves done reading this slot
  }
#undef MFMA16
#undef STAGE2

  // epilogue: C/D layout col=lane&15, row=(lane>>4)*4+reg
  float* outB = out + ((size_t)b * NS + m0) * ND + n0;
#pragma unroll
  for (int i = 0; i < 4; ++i) {
#pragma unroll
    for (int rg = 0; rg < 4; ++rg) {
      int r = i * 16 + q * 4 + rg;
      float* orow = outB + (size_t)r * ND + wn * 64 + l16;
#pragma unroll
      for (int n = 0; n < 4; ++n)
        orow[n * 16] = acc[i][n][rg];
    }
  }
}

// ---------- fallback path (round-1 kernels) in case ws is small ----------
__global__ void anorm_kernel(const float* __restrict__ aspect,
                             unsigned short* __restrict__ a_n) {
  int b = blockIdx.x;
  int t = threadIdx.x;
  const float4* p = (const float4*)(aspect + (size_t)b * ND);
  float4 v = p[t];
  float s = v.x * v.x + v.y * v.y + v.z * v.z + v.w * v.w;
#pragma unroll
  for (int off = 32; off >= 1; off >>= 1) s += __shfl_down(s, off);
  __shared__ float red[4];
  if ((t & 63) == 0) red[t >> 6] = s;
  __syncthreads();
  float tot = red[0] + red[1] + red[2] + red[3];
  float inv = (tot > 0.f) ? (1.f / sqrtf(tot)) : 0.f;
  ushort4 u;
  u.x = f2bf(v.x * inv); u.y = f2bf(v.y * inv);
  u.z = f2bf(v.z * inv); u.w = f2bf(v.w * inv);
  ((ushort4*)(a_n + (size_t)b * ND))[t] = u;
}

__global__ void enorm_kernel(const float* __restrict__ emb,
                             float* __restrict__ inv_norm) {
  int wave = threadIdx.x >> 6;
  int lane = threadIdx.x & 63;
  int row = blockIdx.x * 4 + wave;
  const float4* p = (const float4*)(emb + (size_t)row * ND);
  float s = 0.f;
#pragma unroll
  for (int j = 0; j < 4; ++j) {
    float4 v = p[lane + 64 * j];
    s += v.x * v.x + v.y * v.y + v.z * v.z + v.w * v.w;
  }
#pragma unroll
  for (int off = 32; off >= 1; off >>= 1) s += __shfl_down(s, off);
  if (lane == 0) inv_norm[row] = (s > 0.f) ? (1.f / sqrtf(s)) : 0.f;
}

__global__ __launch_bounds__(256)
void corr_gemm_kernel(const float* __restrict__ emb,
                      const float* __restrict__ inv_norm,
                      const unsigned short* __restrict__ a_n,
                      float* __restrict__ out) {
  __shared__ unsigned short copies[8][2056];
  __shared__ unsigned short Atile[128][40];

  const int nt = blockIdx.x, mt = blockIdx.y, b = blockIdx.z;
  const int n0 = nt * 128, m0 = mt * 128;
  const int t = threadIdx.x;

  {
    const unsigned short* an = a_n + (size_t)b * ND;
    int p = t & 7;
    int x0 = (t >> 3) * 64;
#pragma unroll
    for (int j = 0; j < 64; j += 4) {
      ushort4 u;
      u.x = an[(x0 + j + 0 + p) & 1023];
      u.y = an[(x0 + j + 1 + p) & 1023];
      u.z = an[(x0 + j + 2 + p) & 1023];
      u.w = an[(x0 + j + 3 + p) & 1023];
      *(ushort4*)&copies[p][x0 + j] = u;
    }
  }

  const int ar = t >> 3;
  const int ac = (t & 7) * 4;
  float invn[4];
#pragma unroll
  for (int w = 0; w < 4; ++w)
    invn[w] = inv_norm[b * NS + m0 + ar + 32 * w];

  const int lane = t & 63;
  const int wv = t >> 6;
  const int wm = wv >> 1, wn = wv & 1;
  const int q = lane >> 4, l16 = lane & 15;

  f32x4 acc[4][4];
#pragma unroll
  for (int i = 0; i < 4; ++i)
#pragma unroll
    for (int j = 0; j < 4; ++j)
      acc[i][j] = (f32x4){0.f, 0.f, 0.f, 0.f};

  const float* embB = emb + ((size_t)b * NS + m0) * ND;

  for (int k0 = 0; k0 < ND; k0 += 32) {
    __syncthreads();
#pragma unroll
    for (int w = 0; w < 4; ++w) {
      int r = ar + 32 * w;
      float4 v = *(const float4*)(embB + (size_t)r * ND + k0 + ac);
      float in = invn[w];
      ushort4 u;
      u.x = f2bf(v.x * in); u.y = f2bf(v.y * in);
      u.z = f2bf(v.z * in); u.w = f2bf(v.w * in);
      *(ushort4*)&Atile[r][ac] = u;
    }
    __syncthreads();

    bf16x8 af[4], bfr[4];
#pragma unroll
    for (int r = 0; r < 4; ++r) {
      int m = wm * 64 + r * 16 + l16;
      af[r] = *(const bf16x8*)&Atile[m][q * 8];
    }
#pragma unroll
    for (int r = 0; r < 4; ++r) {
      int ng = n0 + wn * 64 + r * 16 + l16;
      int e0 = k0 + 8 * q - ng + 1024;
      int p = e0 & 7;
      bfr[r] = *(const bf16x8*)&copies[p][e0 - p];
    }
#pragma unroll
    for (int i = 0; i < 4; ++i)
#pragma unroll
      for (int j = 0; j < 4; ++j)
        acc[i][j] = __builtin_amdgcn_mfma_f32_16x16x32_bf16(af[i], bfr[j], acc[i][j], 0, 0, 0);
  }

  float* outB = out + ((size_t)b * NS + m0) * ND + n0;
#pragma unroll
  for (int i = 0; i < 4; ++i) {
#pragma unroll
    for (int rg = 0; rg < 4; ++rg) {
      int s = wm * 64 + i * 16 + q * 4 + rg;
      float* orow = outB + (size_t)s * ND + wn * 64 + l16;
#pragma unroll
      for (int j = 0; j < 4; ++j)
        orow[j * 16] = acc[i][j][rg];
    }
  }
}

extern "C" void kernel_launch(void* const* d_in, const int* in_sizes, int n_in,
                              void* d_out, int out_size, void* d_ws, size_t ws_size,
                              hipStream_t stream) {
  const float* emb = (const float*)d_in[0];
  const float* aspect = (const float*)d_in[1];
  float* out = (float*)d_out;

  const size_t need = 65536 + (size_t)NB * NS * ND * 2;  // a_n + eN(bf16)

  if (ws_size >= need) {
    unsigned short* a_n = (unsigned short*)d_ws;
    unsigned short* eN = (unsigned short*)((char*)d_ws + 65536);
    enormbf_fused_kernel<<<4096, 256, 0, stream>>>(emb, eN, aspect, a_n);
    // grid (b, mt, nt): flat id = b + 32*(mt + 8*nt) -> XCD = b%8; all 32 tiles
    // of batch b share an XCD -> eN panel + a_n L2 reuse across mt/nt siblings.
    corr_gemm9_kernel<<<dim3(NB, 8, 4), 256, 0, stream>>>(eN, a_n, out);
  } else {
    float* inv_norm = (float*)d_ws;
    unsigned short* a_n = (unsigned short*)((char*)d_ws + 65536);
    enorm_kernel<<<4096, 256, 0, stream>>>(emb, inv_norm);
    anorm_kernel<<<NB, 256, 0, stream>>>(aspect, a_n);
    corr_gemm_kernel<<<dim3(8, 4, NB), 256, 0, stream>>>(emb, inv_norm, a_n, out);
  }
}

// Round 7
// 145.473 us; speedup vs baseline: 1.0013x; 1.0013x over previous
//
#include <hip/hip_runtime.h>
#include <hip/hip_bf16.h>

typedef __attribute__((ext_vector_type(8))) short bf16x8;
typedef __attribute__((ext_vector_type(4))) float f32x4;

#define NB 32
#define NS 512
#define ND 1024

__device__ __forceinline__ unsigned short f2bf(float f) {
  unsigned int u = __float_as_uint(f);
  u = (u + 0x7FFFu + ((u >> 16) & 1u)) >> 16;  // RNE
  return (unsigned short)u;
}

// ---------- normalized embeddings -> bf16 ----------
__global__ __launch_bounds__(256)
void enormbf_kernel2(const float* __restrict__ emb,
                     unsigned short* __restrict__ eN) {
  int wave = threadIdx.x >> 6, lane = threadIdx.x & 63;
  size_t row = (size_t)blockIdx.x * 4 + wave;  // 0..16383
  const float4* p = (const float4*)(emb + row * ND);
  float4 v[4];
  float s = 0.f;
#pragma unroll
  for (int j = 0; j < 4; ++j) {
    v[j] = p[lane + 64 * j];
    s += v[j].x * v[j].x + v[j].y * v[j].y + v[j].z * v[j].z + v[j].w * v[j].w;
  }
#pragma unroll
  for (int off = 32; off >= 1; off >>= 1) s += __shfl_xor(s, off);
  float inv = (s > 0.f) ? (1.f / sqrtf(s)) : 0.f;
  ushort4* o = (ushort4*)(eN + row * ND);
#pragma unroll
  for (int j = 0; j < 4; ++j) {
    ushort4 u;
    u.x = f2bf(v[j].x * inv); u.y = f2bf(v[j].y * inv);
    u.z = f2bf(v[j].z * inv); u.w = f2bf(v[j].w * inv);
    o[lane + 64 * j] = u;
  }
}

// ---------- normalized aspect -> 8 shifted copies in GLOBAL ws ----------
// a_n8[b][p][x] = a_n[(x+p) & 1023], x in [0,2048): every circulant B-fragment
// becomes a 16B-aligned global_load_dwordx4 from a 32KB/batch L1/L2 window.
__global__ void anorm8_kernel(const float* __restrict__ aspect,
                              unsigned short* __restrict__ a_n8) {
  int b = blockIdx.x;
  int t = threadIdx.x;
  __shared__ float red[4];
  __shared__ unsigned short sm[1024];
  const float4* pa = (const float4*)(aspect + (size_t)b * ND);
  float4 v = pa[t];
  float s = v.x * v.x + v.y * v.y + v.z * v.z + v.w * v.w;
#pragma unroll
  for (int off = 32; off >= 1; off >>= 1) s += __shfl_down(s, off);
  if ((t & 63) == 0) red[t >> 6] = s;
  __syncthreads();
  float tot = red[0] + red[1] + red[2] + red[3];
  float inv = (tot > 0.f) ? (1.f / sqrtf(tot)) : 0.f;
  sm[t * 4 + 0] = f2bf(v.x * inv);
  sm[t * 4 + 1] = f2bf(v.y * inv);
  sm[t * 4 + 2] = f2bf(v.z * inv);
  sm[t * 4 + 3] = f2bf(v.w * inv);
  __syncthreads();
  unsigned short* dst = a_n8 + (size_t)b * 16384;
#pragma unroll
  for (int p = 0; p < 8; ++p) {
    ushort4 u;
    u.x = sm[(t * 4 + 0 + p) & 1023];
    u.y = sm[(t * 4 + 1 + p) & 1023];
    u.z = sm[(t * 4 + 2 + p) & 1023];
    u.w = sm[(t * 4 + 3 + p) & 1023];
    *(ushort4*)(dst + p * 2048 + t * 4) = u;          // x and x+1024 hold the
    *(ushort4*)(dst + p * 2048 + 1024 + t * 4) = u;   // same values (mod 1024)
  }
}

// ---------- GEMM v10: 128x256 tile, 4 waves (wave-tile 128x64), A-only LDS
// (ring-3 via global_load_lds, 48KB), B direct from global a_n8 (L1/L2-hot,
// TA pipe -> off the LDS pipe). Counted vmcnt/lgkm, 1 barrier/tile.
// LDS floor halves vs v9: A-only 2048 b128-reads/CU = 10.2us vs MFMA 16.6us.
__global__ __launch_bounds__(256, 2)
void corr_gemm10_kernel(const unsigned short* __restrict__ eN,
                        const unsigned short* __restrict__ a_n8,
                        float* __restrict__ out) {
  __shared__ __align__(16) unsigned short Alds[3 * 8192];  // 3 x 128 x 64

  const int b = blockIdx.x, mt = blockIdx.y, nt = blockIdx.z;
  const int n0 = nt * 256, m0 = mt * 128;
  const int tid = threadIdx.x;

  const int lane = tid & 63, wn = tid >> 6;  // 4 waves = 4 col-quarters (128x64)
  const int q = lane >> 4, l16 = lane & 15;
  const int mx = l16 & 7;
  const int s00 = (q ^ mx) * 8;              // chunk q     (kk=0)
  const int s01 = ((4 + q) ^ mx) * 8;        // chunk 4+q   (kk=1)
  const int arow = l16 * 64;

  // B from global: value needed = a_n[(d - i) mod 1024], folded index
  // G = G0 + kt*64 + kk*32 - n*16 in [1,2040]; p = G&7 = (8-mx)&7 const/lane;
  // addr = a_n8 + b*16384 + p*2048 + (G - p)  -> 16B-aligned dwordx4.
  const int pB = (8 - mx) & 7;
  const int G0 = 1024 + 8 * q - wn * 64 - l16 - n0;
  const unsigned short* Bbase = a_n8 + (size_t)b * 16384 + pB * 2048 + (G0 - pB);

  // A staging source (inverse chunk swizzle); LDS dst = slot + tid*16 + j*4096
  const unsigned short* gstage =
      eN + ((size_t)b * NS + m0 + (tid >> 3)) * ND + (size_t)(((tid & 7) ^ ((tid >> 3) & 7)) * 8);
  char* ldsAbase = (char*)Alds;

  f32x4 acc[8][4];
#pragma unroll
  for (int i = 0; i < 8; ++i)
#pragma unroll
    for (int j = 0; j < 4; ++j)
      acc[i][j] = (f32x4){0.f, 0.f, 0.f, 0.f};

  bf16x8 a0[4], a1[4], bfr[4][2];

#define ISSUE_A(DST, BASE, PHN)                                          \
  do {                                                                   \
    DST[0] = *(const bf16x8*)&(BASE)[arow + (PHN) * 2048 + s00];         \
    DST[1] = *(const bf16x8*)&(BASE)[arow + (PHN) * 2048 + s01];         \
    DST[2] = *(const bf16x8*)&(BASE)[arow + (PHN) * 2048 + 1024 + s00];  \
    DST[3] = *(const bf16x8*)&(BASE)[arow + (PHN) * 2048 + 1024 + s01];  \
  } while (0)

#define STAGE4(SLOT, KTT)                                                              \
  do {                                                                                 \
    const unsigned short* sg_ = gstage + (size_t)(KTT) * 64;                           \
    char* dl_ = ldsAbase + (SLOT) * 16384 + (size_t)tid * 16;                          \
    _Pragma("unroll")                                                                  \
    for (int j = 0; j < 4; ++j)                                                        \
      __builtin_amdgcn_global_load_lds(                                                \
          (const __attribute__((address_space(1))) void*)(sg_ + (size_t)j * 32 * ND),  \
          (__attribute__((address_space(3))) void*)(dl_ + j * 4096), 16, 0, 0);        \
  } while (0)

#define LOADB(KTT)                                                  \
  do {                                                              \
    const unsigned short* Bt = Bbase + (KTT) * 64;                  \
    _Pragma("unroll")                                               \
    for (int n = 0; n < 4; ++n) {                                   \
      bfr[n][0] = *(const bf16x8*)(Bt - n * 16);                    \
      bfr[n][1] = *(const bf16x8*)(Bt + 32 - n * 16);               \
    }                                                               \
  } while (0)

#define MFMA_PH(PH, CS)                                                                       \
  do {                                                                                        \
    __builtin_amdgcn_s_setprio(1);                                                            \
    _Pragma("unroll")                                                                         \
    for (int n = 0; n < 4; ++n) {                                                             \
      acc[2*(PH)][n]   = __builtin_amdgcn_mfma_f32_16x16x32_bf16(CS[0], bfr[n][0], acc[2*(PH)][n],   0, 0, 0); \
      acc[2*(PH)][n]   = __builtin_amdgcn_mfma_f32_16x16x32_bf16(CS[1], bfr[n][1], acc[2*(PH)][n],   0, 0, 0); \
      acc[2*(PH)+1][n] = __builtin_amdgcn_mfma_f32_16x16x32_bf16(CS[2], bfr[n][0], acc[2*(PH)+1][n], 0, 0, 0); \
      acc[2*(PH)+1][n] = __builtin_amdgcn_mfma_f32_16x16x32_bf16(CS[3], bfr[n][1], acc[2*(PH)+1][n], 0, 0, 0); \
    }                                                                                         \
    __builtin_amdgcn_s_setprio(0);                                                            \
  } while (0)

  // ---- prologue: stage tiles 0,1; confirm own slot-0 loads; cross-wave barrier ----
  STAGE4(0, 0);
  STAGE4(1, 1);
  asm volatile("s_waitcnt vmcnt(4)" ::: "memory");  // slot0 retired; slot1 in flight
  __builtin_amdgcn_sched_barrier(0);
  __builtin_amdgcn_s_barrier();                     // slot0 visible to all waves

  int c0 = 0, c1 = 1, c2 = 2;

  // Invariant entering tile kt: outstanding vmem = stage(kt+1)[4] only.
#pragma unroll 1
  for (int kt = 0; kt < 16; ++kt) {
    const unsigned short* At = Alds + c0 * 8192;

    LOADB(kt);                                  // 8 vm (L1/L2-hot)
    __builtin_amdgcn_sched_barrier(0);          // pin: B before stage (vmcnt order)
    if (kt < 14) STAGE4(c2, kt + 2);            // 4 vm
    __builtin_amdgcn_sched_barrier(0);

    ISSUE_A(a0, At, 0);                         // 4 lgkm (slot safe since last seam)
    ISSUE_A(a1, At, 1);                         // 4 lgkm -> LDS service overlaps B latency

    if (kt < 14) {
      asm volatile("s_waitcnt vmcnt(4)" ::: "memory");  // B(kt)+stage(kt+1) done; stage(kt+2) in flight
    } else {
      asm volatile("s_waitcnt vmcnt(0)" ::: "memory");  // tail: drain all
    }
    __builtin_amdgcn_sched_barrier(0);

    asm volatile("s_waitcnt lgkmcnt(4)" ::: "memory");  // a0 ready; a1 in flight
    __builtin_amdgcn_sched_barrier(0);
    MFMA_PH(0, a0);

    ISSUE_A(a0, At, 2);
    asm volatile("s_waitcnt lgkmcnt(4)" ::: "memory");
    __builtin_amdgcn_sched_barrier(0);
    MFMA_PH(1, a1);

    ISSUE_A(a1, At, 3);
    asm volatile("s_waitcnt lgkmcnt(4)" ::: "memory");
    __builtin_amdgcn_sched_barrier(0);
    MFMA_PH(2, a0);

    asm volatile("s_waitcnt lgkmcnt(0)" ::: "memory");
    __builtin_amdgcn_sched_barrier(0);
    MFMA_PH(3, a1);

    __builtin_amdgcn_s_barrier();  // seam: all waves done with c0; stage-confirm done

    int tmp = c0; c0 = c1; c1 = c2; c2 = tmp;
  }
#undef MFMA_PH
#undef LOADB
#undef STAGE4
#undef ISSUE_A

  // epilogue: C/D layout col=lane&15, row=(lane>>4)*4+reg
  float* outB = out + ((size_t)b * NS + m0) * ND + n0;
#pragma unroll
  for (int i = 0; i < 8; ++i) {
#pragma unroll
    for (int rg = 0; rg < 4; ++rg) {
      int r = i * 16 + q * 4 + rg;
      float* orow = outB + (size_t)r * ND + wn * 64 + l16;
#pragma unroll
      for (int n = 0; n < 4; ++n)
        orow[n * 16] = acc[i][n][rg];
    }
  }
}

// ---------- middle path (R6 kernels: plain a_n + LDS copies) ----------
__global__ void anorm_kernel(const float* __restrict__ aspect,
                             unsigned short* __restrict__ a_n) {
  int b = blockIdx.x;
  int t = threadIdx.x;
  const float4* p = (const float4*)(aspect + (size_t)b * ND);
  float4 v = p[t];
  float s = v.x * v.x + v.y * v.y + v.z * v.z + v.w * v.w;
#pragma unroll
  for (int off = 32; off >= 1; off >>= 1) s += __shfl_down(s, off);
  __shared__ float red[4];
  if ((t & 63) == 0) red[t >> 6] = s;
  __syncthreads();
  float tot = red[0] + red[1] + red[2] + red[3];
  float inv = (tot > 0.f) ? (1.f / sqrtf(tot)) : 0.f;
  ushort4 u;
  u.x = f2bf(v.x * inv); u.y = f2bf(v.y * inv);
  u.z = f2bf(v.z * inv); u.w = f2bf(v.w * inv);
  ((ushort4*)(a_n + (size_t)b * ND))[t] = u;
}

__global__ __launch_bounds__(256)
void corr_gemm9_kernel(const unsigned short* __restrict__ eN,
                       const unsigned short* __restrict__ a_n,
                       float* __restrict__ out) {
  __shared__ __align__(16) unsigned short Alds[2 * 4096];
  __shared__ __align__(16) unsigned short copies[8 * 1288];

  const int b = blockIdx.x, mt = blockIdx.y, nt = blockIdx.z;
  const int n0 = nt * 256, m0 = mt * 64;
  const int tid = threadIdx.x;

  const int lane = tid & 63, wn = tid >> 6;
  const int q = lane >> 4, l16 = lane & 15;
  const int mx = l16 & 7;
  const int s00 = (q ^ mx) * 8;
  const int s01 = ((4 + q) ^ mx) * 8;
  const int arow = l16 * 64;

  const int pB = (8 - mx) & 7;
  const unsigned short* Bp = copies + pB * 1287 + (256 + 8 * q - wn * 64 - l16);

  const unsigned short* gstage =
      eN + ((size_t)b * NS + m0 + (tid >> 3)) * ND + (size_t)(((tid & 7) ^ ((tid >> 3) & 7)) * 8);
  char* ldsAbase = (char*)Alds;

  unsigned short av[40];
  {
    const unsigned short* an = a_n + (size_t)b * ND;
    const int p = tid & 7;
    const int x0 = (tid >> 3) * 40;
    const int base = (768 - n0 + p) & 1023;
#pragma unroll
    for (int j = 0; j < 40; ++j) av[j] = an[(base + x0 + j) & 1023];
  }

#pragma unroll
  for (int j = 0; j < 2; ++j)
    __builtin_amdgcn_global_load_lds(
        (const __attribute__((address_space(1))) void*)(gstage + (size_t)j * 32 * ND),
        (__attribute__((address_space(3))) void*)(ldsAbase + (size_t)tid * 16 + j * 4096),
        16, 0, 0);

  {
    const int p = tid & 7;
    const int x0 = (tid >> 3) * 40;
#pragma unroll
    for (int j = 0; j < 40; ++j) copies[p * 1288 + x0 + j] = av[j];
  }

  f32x4 acc[4][4];
#pragma unroll
  for (int i = 0; i < 4; ++i)
#pragma unroll
    for (int j = 0; j < 4; ++j)
      acc[i][j] = (f32x4){0.f, 0.f, 0.f, 0.f};

  asm volatile("s_waitcnt lgkmcnt(0)" ::: "memory");
  __builtin_amdgcn_sched_barrier(0);
  __builtin_amdgcn_s_barrier();
  asm volatile("s_waitcnt vmcnt(0)" ::: "memory");
  __builtin_amdgcn_sched_barrier(0);
  __builtin_amdgcn_s_barrier();

  bf16x8 a0[4], a1[4], b0[4], b1[4];

#pragma unroll 1
  for (int kt = 0; kt < 16; ++kt) {
    const unsigned short* At = Alds + (kt & 1) * 4096;

    if (kt < 15) {
      const unsigned short* sg_ = gstage + (size_t)(kt + 1) * 64;
      char* dl_ = ldsAbase + ((kt & 1) ^ 1) * 8192 + (size_t)tid * 16;
#pragma unroll
      for (int j = 0; j < 2; ++j)
        __builtin_amdgcn_global_load_lds(
            (const __attribute__((address_space(1))) void*)(sg_ + (size_t)j * 32 * ND),
            (__attribute__((address_space(3))) void*)(dl_ + j * 4096), 16, 0, 0);
    }

    const unsigned short* Bt = Bp + kt * 64;
#pragma unroll
    for (int r = 0; r < 4; ++r) a0[r] = *(const bf16x8*)&At[arow + r * 1024 + s00];
#pragma unroll
    for (int n = 0; n < 4; ++n) b0[n] = *(const bf16x8*)(Bt - n * 16);
#pragma unroll
    for (int r = 0; r < 4; ++r) a1[r] = *(const bf16x8*)&At[arow + r * 1024 + s01];
#pragma unroll
    for (int n = 0; n < 4; ++n) b1[n] = *(const bf16x8*)(Bt + 32 - n * 16);

    asm volatile("s_waitcnt lgkmcnt(8)" ::: "memory");
    __builtin_amdgcn_sched_barrier(0);
    __builtin_amdgcn_s_setprio(1);
#pragma unroll
    for (int n = 0; n < 4; ++n)
#pragma unroll
      for (int r = 0; r < 4; ++r)
        acc[r][n] = __builtin_amdgcn_mfma_f32_16x16x32_bf16(a0[r], b0[n], acc[r][n], 0, 0, 0);
    __builtin_amdgcn_s_setprio(0);

    asm volatile("s_waitcnt lgkmcnt(0)" ::: "memory");
    __builtin_amdgcn_sched_barrier(0);
    __builtin_amdgcn_s_setprio(1);
#pragma unroll
    for (int n = 0; n < 4; ++n)
#pragma unroll
      for (int r = 0; r < 4; ++r)
        acc[r][n] = __builtin_amdgcn_mfma_f32_16x16x32_bf16(a1[r], b1[n], acc[r][n], 0, 0, 0);
    __builtin_amdgcn_s_setprio(0);

    asm volatile("s_waitcnt vmcnt(0)" ::: "memory");
    __builtin_amdgcn_sched_barrier(0);
    __builtin_amdgcn_s_barrier();
  }

  float* outB = out + ((size_t)b * NS + m0) * ND + n0;
#pragma unroll
  for (int i = 0; i < 4; ++i) {
#pragma unroll
    for (int rg = 0; rg < 4; ++rg) {
      int r = i * 16 + q * 4 + rg;
      float* orow = outB + (size_t)r * ND + wn * 64 + l16;
#pragma unroll
      for (int n = 0; n < 4; ++n)
        orow[n * 16] = acc[i][n][rg];
    }
  }
}

// ---------- small-ws fallback (round-1 kernels) ----------
__global__ void enorm_kernel(const float* __restrict__ emb,
                             float* __restrict__ inv_norm) {
  int wave = threadIdx.x >> 6;
  int lane = threadIdx.x & 63;
  int row = blockIdx.x * 4 + wave;
  const float4* p = (const float4*)(emb + (size_t)row * ND);
  float s = 0.f;
#pragma unroll
  for (int j = 0; j < 4; ++j) {
    float4 v = p[lane + 64 * j];
    s += v.x * v.x + v.y * v.y + v.z * v.z + v.w * v.w;
  }
#pragma unroll
  for (int off = 32; off >= 1; off >>= 1) s += __shfl_down(s, off);
  if (lane == 0) inv_norm[row] = (s > 0.f) ? (1.f / sqrtf(s)) : 0.f;
}

__global__ __launch_bounds__(256)
void corr_gemm_kernel(const float* __restrict__ emb,
                      const float* __restrict__ inv_norm,
                      const unsigned short* __restrict__ a_n,
                      float* __restrict__ out) {
  __shared__ unsigned short copies[8][2056];
  __shared__ unsigned short Atile[128][40];

  const int nt = blockIdx.x, mt = blockIdx.y, b = blockIdx.z;
  const int n0 = nt * 128, m0 = mt * 128;
  const int t = threadIdx.x;

  {
    const unsigned short* an = a_n + (size_t)b * ND;
    int p = t & 7;
    int x0 = (t >> 3) * 64;
#pragma unroll
    for (int j = 0; j < 64; j += 4) {
      ushort4 u;
      u.x = an[(x0 + j + 0 + p) & 1023];
      u.y = an[(x0 + j + 1 + p) & 1023];
      u.z = an[(x0 + j + 2 + p) & 1023];
      u.w = an[(x0 + j + 3 + p) & 1023];
      *(ushort4*)&copies[p][x0 + j] = u;
    }
  }

  const int ar = t >> 3;
  const int ac = (t & 7) * 4;
  float invn[4];
#pragma unroll
  for (int w = 0; w < 4; ++w)
    invn[w] = inv_norm[b * NS + m0 + ar + 32 * w];

  const int lane = t & 63;
  const int wv = t >> 6;
  const int wm = wv >> 1, wn = wv & 1;
  const int q = lane >> 4, l16 = lane & 15;

  f32x4 acc[4][4];
#pragma unroll
  for (int i = 0; i < 4; ++i)
#pragma unroll
    for (int j = 0; j < 4; ++j)
      acc[i][j] = (f32x4){0.f, 0.f, 0.f, 0.f};

  const float* embB = emb + ((size_t)b * NS + m0) * ND;

  for (int k0 = 0; k0 < ND; k0 += 32) {
    __syncthreads();
#pragma unroll
    for (int w = 0; w < 4; ++w) {
      int r = ar + 32 * w;
      float4 v = *(const float4*)(embB + (size_t)r * ND + k0 + ac);
      float in = invn[w];
      ushort4 u;
      u.x = f2bf(v.x * in); u.y = f2bf(v.y * in);
      u.z = f2bf(v.z * in); u.w = f2bf(v.w * in);
      *(ushort4*)&Atile[r][ac] = u;
    }
    __syncthreads();

    bf16x8 af[4], bfr[4];
#pragma unroll
    for (int r = 0; r < 4; ++r) {
      int m = wm * 64 + r * 16 + l16;
      af[r] = *(const bf16x8*)&Atile[m][q * 8];
    }
#pragma unroll
    for (int r = 0; r < 4; ++r) {
      int ng = n0 + wn * 64 + r * 16 + l16;
      int e0 = k0 + 8 * q - ng + 1024;
      int p = e0 & 7;
      bfr[r] = *(const bf16x8*)&copies[p][e0 - p];
    }
#pragma unroll
    for (int i = 0; i < 4; ++i)
#pragma unroll
      for (int j = 0; j < 4; ++j)
        acc[i][j] = __builtin_amdgcn_mfma_f32_16x16x32_bf16(af[i], bfr[j], acc[i][j], 0, 0, 0);
  }

  float* outB = out + ((size_t)b * NS + m0) * ND + n0;
#pragma unroll
  for (int i = 0; i < 4; ++i) {
#pragma unroll
    for (int rg = 0; rg < 4; ++rg) {
      int s = wm * 64 + i * 16 + q * 4 + rg;
      float* orow = outB + (size_t)s * ND + wn * 64 + l16;
#pragma unroll
      for (int j = 0; j < 4; ++j)
        orow[j * 16] = acc[i][j][rg];
    }
  }
}

extern "C" void kernel_launch(void* const* d_in, const int* in_sizes, int n_in,
                              void* d_out, int out_size, void* d_ws, size_t ws_size,
                              hipStream_t stream) {
  const float* emb = (const float*)d_in[0];
  const float* aspect = (const float*)d_in[1];
  float* out = (float*)d_out;

  const size_t eN_bytes = (size_t)NB * NS * ND * 2;
  const size_t need10 = 1048576 + eN_bytes;       // a_n8 (1MB) + eN
  const size_t need9 = 65536 + eN_bytes;          // a_n (64KB pad) + eN

  if (ws_size >= need10) {
    unsigned short* a_n8 = (unsigned short*)d_ws;
    unsigned short* eN = (unsigned short*)((char*)d_ws + 1048576);
    anorm8_kernel<<<NB, 256, 0, stream>>>(aspect, a_n8);
    enormbf_kernel2<<<4096, 256, 0, stream>>>(emb, eN);
    // grid (b, mt, nt): flat = b + 32*(mt + 4*nt) -> XCD = b%8; all 16 tiles
    // of batch b share an XCD -> eN panel + a_n8 L1/L2 reuse.
    corr_gemm10_kernel<<<dim3(NB, 4, 4), 256, 0, stream>>>(eN, a_n8, out);
  } else if (ws_size >= need9) {
    unsigned short* a_n = (unsigned short*)d_ws;
    unsigned short* eN = (unsigned short*)((char*)d_ws + 65536);
    anorm_kernel<<<NB, 256, 0, stream>>>(aspect, a_n);
    enormbf_kernel2<<<4096, 256, 0, stream>>>(emb, eN);
    corr_gemm9_kernel<<<dim3(NB, 8, 4), 256, 0, stream>>>(eN, a_n, out);
  } else {
    float* inv_norm = (float*)d_ws;
    unsigned short* a_n = (unsigned short*)((char*)d_ws + 65536);
    enorm_kernel<<<4096, 256, 0, stream>>>(emb, inv_norm);
    anorm_kernel<<<NB, 256, 0, stream>>>(aspect, a_n);
    corr_gemm_kernel<<<dim3(8, 4, NB), 256, 0, stream>>>(emb, inv_norm, a_n, out);
  }
}

// Round 8
// 138.613 us; speedup vs baseline: 1.0508x; 1.0495x over previous
//
#include <hip/hip_runtime.h>
#include <hip/hip_bf16.h>

typedef __attribute__((ext_vector_type(8))) short bf16x8;
typedef __attribute__((ext_vector_type(4))) float f32x4;
typedef __attribute__((ext_vector_type(4))) unsigned int u32x4;

#define NB 32
#define NS 512
#define ND 1024

__device__ __forceinline__ unsigned short f2bf(float f) {
  unsigned int u = __float_as_uint(f);
  u = (u + 0x7FFFu + ((u >> 16) & 1u)) >> 16;  // RNE
  return (unsigned short)u;
}

// ---------- normalized aspect -> bf16 ----------
__global__ void anorm_kernel(const float* __restrict__ aspect,
                             unsigned short* __restrict__ a_n) {
  int b = blockIdx.x;
  int t = threadIdx.x;
  const float4* p = (const float4*)(aspect + (size_t)b * ND);
  float4 v = p[t];
  float s = v.x * v.x + v.y * v.y + v.z * v.z + v.w * v.w;
#pragma unroll
  for (int off = 32; off >= 1; off >>= 1) s += __shfl_down(s, off);
  __shared__ float red[4];
  if ((t & 63) == 0) red[t >> 6] = s;
  __syncthreads();
  float tot = red[0] + red[1] + red[2] + red[3];
  float inv = (tot > 0.f) ? (1.f / sqrtf(tot)) : 0.f;
  ushort4 u;
  u.x = f2bf(v.x * inv); u.y = f2bf(v.y * inv);
  u.z = f2bf(v.z * inv); u.w = f2bf(v.w * inv);
  ((ushort4*)(a_n + (size_t)b * ND))[t] = u;
}

// ---------- GEMM v11: NORM FUSED INTO GEMM — the eN pass is deleted.
// (1/||e||)E . B == diag-scale of (E.B): stage raw f32 emb -> cvt bf16 in regs
// -> LDS (same XOR chunk layout as v8); accumulate per-row sumsq during cvt
// (free: VALU ~90% idle); scale by rsqrt in epilogue. B via LDS circulant
// copies (v8's proven path). 128x256 tile, 4 waves, dbuf A, counted lgkm,
// 1 barrier/tile, 2 blocks/CU (LDS 53.9 KB).
__global__ __launch_bounds__(256, 2)
void corr_gemm11_kernel(const float* __restrict__ emb,
                        const unsigned short* __restrict__ a_n,
                        float* __restrict__ out) {
  __shared__ __align__(16) unsigned short Abuf[2][128][64];   // 32 KB (bf16)
  __shared__ __align__(16) unsigned short copies[8 * 1288];   // 20.6 KB
  __shared__ float invnLDS[128];                              // 0.5 KB

  const int b = blockIdx.x, mt = blockIdx.y, nt = blockIdx.z;
  const int n0 = nt * 256, m0 = mt * 128;
  const int tid = threadIdx.x;

  const int lane = tid & 63, wn = tid >> 6;  // 4 waves = 4 col-quarters (128x64)
  const int q = lane >> 4, l16 = lane & 15;
  const int mx = l16 & 7;
  const int s00 = (q ^ mx) * 8;              // chunk q     (kk=0)
  const int s01 = ((4 + q) ^ mx) * 8;        // chunk 4+q   (kk=1)

  // B read base (v8 verbatim): addr = copies + pB*1287 + idx,
  // idx = kt*64 + kk*32 + 8q + 256 - n_local, idx&7 == pB.
  const int pB = (8 - mx) & 7;
  const unsigned short* Bp = copies + pB * 1287 + (256 + 8 * q - wn * 64 - l16);

  // A staging: thread t owns rows r0+32j (j=0..3), global col-chunk cw (8 f32);
  // writes bf16 to LDS slot sw = cw ^ (r&7)  (r&7 == r0&7 since 32|32j).
  const int r0 = tid >> 3, cw = tid & 7;
  const int sw = cw ^ (r0 & 7);
  const float* gA = emb + ((size_t)b * NS + m0 + r0) * ND + cw * 8;

  // ---- prologue 1: gather a_n window into regs ----
  unsigned short av[40];
  {
    const unsigned short* an = a_n + (size_t)b * ND;
    const int p = tid & 7;
    const int x0 = (tid >> 3) * 40;  // 32 threads/copy x 40 = 1280
    const int base = (768 - n0 + p) & 1023;
#pragma unroll
    for (int j = 0; j < 40; ++j) av[j] = an[(base + x0 + j) & 1023];
  }

  float4 g[8];                       // staged f32 (2 float4 per row-slice)
  float ss0 = 0.f, ss1 = 0.f, ss2 = 0.f, ss3 = 0.f;  // per-row sumsq

#define LOADG(KTT)                                                       \
  do {                                                                   \
    _Pragma("unroll")                                                    \
    for (int j = 0; j < 4; ++j) {                                        \
      const float* _p = gA + (size_t)j * 32 * ND + (KTT) * 64;           \
      g[2 * j] = *(const float4*)_p;                                     \
      g[2 * j + 1] = *(const float4*)(_p + 4);                           \
    }                                                                    \
  } while (0)

#define CVT_WRITE(NBUF)                                                  \
  do {                                                                   \
    _Pragma("unroll")                                                    \
    for (int j = 0; j < 4; ++j) {                                        \
      float4 va = g[2 * j], vb = g[2 * j + 1];                           \
      float _s = va.x * va.x + va.y * va.y + va.z * va.z + va.w * va.w   \
               + vb.x * vb.x + vb.y * vb.y + vb.z * vb.z + vb.w * vb.w;  \
      if (j == 0) ss0 += _s; else if (j == 1) ss1 += _s;                 \
      else if (j == 2) ss2 += _s; else ss3 += _s;                        \
      u32x4 w;                                                           \
      w[0] = (unsigned)f2bf(va.x) | ((unsigned)f2bf(va.y) << 16);        \
      w[1] = (unsigned)f2bf(va.z) | ((unsigned)f2bf(va.w) << 16);        \
      w[2] = (unsigned)f2bf(vb.x) | ((unsigned)f2bf(vb.y) << 16);        \
      w[3] = (unsigned)f2bf(vb.z) | ((unsigned)f2bf(vb.w) << 16);       \
      *(u32x4*)&Abuf[NBUF][r0 + 32 * j][sw * 8] = w;                     \
    }                                                                    \
  } while (0)

  // ---- prologue 2: stage tile 0 (regs), write copies, cvt tile 0, load tile 1 ----
  LOADG(0);                       // 8 vm in flight
  {
    const int p = tid & 7;
    const int x0 = (tid >> 3) * 40;
#pragma unroll
    for (int j = 0; j < 40; ++j) copies[p * 1288 + x0 + j] = av[j];
  }
  CVT_WRITE(0);                   // compiler waits vmcnt for g[]
  LOADG(1);                       // tile 1 in flight across tile 0's compute
  __syncthreads();                // copies + Abuf[0] visible block-wide

  f32x4 acc[8][4];
#pragma unroll
  for (int i = 0; i < 8; ++i)
#pragma unroll
    for (int j = 0; j < 4; ++j)
      acc[i][j] = (f32x4){0.f, 0.f, 0.f, 0.f};

  bf16x8 a0[4], a1[4], bfr[4][2];

#define ISSUE_A(DST, BASE, PHN)                                             \
  do {                                                                      \
    DST[0] = *(const bf16x8*)&(BASE)[(PHN) * 32 + l16][s00];                \
    DST[1] = *(const bf16x8*)&(BASE)[(PHN) * 32 + l16][s01];                \
    DST[2] = *(const bf16x8*)&(BASE)[(PHN) * 32 + 16 + l16][s00];           \
    DST[3] = *(const bf16x8*)&(BASE)[(PHN) * 32 + 16 + l16][s01];           \
  } while (0)

#define LOAD_B(KTT)                                                 \
  do {                                                              \
    const unsigned short* Bt = Bp + (KTT) * 64;                     \
    _Pragma("unroll")                                               \
    for (int n = 0; n < 4; ++n) {                                   \
      bfr[n][0] = *(const bf16x8*)(Bt - n * 16);                    \
      bfr[n][1] = *(const bf16x8*)(Bt + 32 - n * 16);               \
    }                                                               \
  } while (0)

#define MFMA_PH(PH, CS)                                                                       \
  do {                                                                                        \
    __builtin_amdgcn_s_setprio(1);                                                            \
    _Pragma("unroll")                                                                         \
    for (int n = 0; n < 4; ++n) {                                                             \
      acc[2*(PH)][n]   = __builtin_amdgcn_mfma_f32_16x16x32_bf16(CS[0], bfr[n][0], acc[2*(PH)][n],   0, 0, 0); \
      acc[2*(PH)][n]   = __builtin_amdgcn_mfma_f32_16x16x32_bf16(CS[1], bfr[n][1], acc[2*(PH)][n],   0, 0, 0); \
      acc[2*(PH)+1][n] = __builtin_amdgcn_mfma_f32_16x16x32_bf16(CS[2], bfr[n][0], acc[2*(PH)+1][n], 0, 0, 0); \
      acc[2*(PH)+1][n] = __builtin_amdgcn_mfma_f32_16x16x32_bf16(CS[3], bfr[n][1], acc[2*(PH)+1][n], 0, 0, 0); \
    }                                                                                         \
    __builtin_amdgcn_s_setprio(0);                                                            \
  } while (0)

  // Invariant entering tile kt: Abuf[kt&1] holds tile kt (all waves, via barrier);
  // g[] holds tile kt+1's f32 (issued last tile, vmcnt pending).
#pragma unroll 1
  for (int kt = 0; kt < 16; ++kt) {
    const unsigned short (*At)[64] = Abuf[kt & 1];

    ISSUE_A(a0, At, 0);                         // 4 lgkm
    LOAD_B(kt);                                 // 8 lgkm
    ISSUE_A(a1, At, 1);                         // 4 lgkm -> 16 outstanding
    asm volatile("s_waitcnt lgkmcnt(4)" ::: "memory");  // a0+B ready; a1 in flight
    __builtin_amdgcn_sched_barrier(0);
    MFMA_PH(0, a0);

    ISSUE_A(a0, At, 2);
    asm volatile("s_waitcnt lgkmcnt(4)" ::: "memory");
    __builtin_amdgcn_sched_barrier(0);
    MFMA_PH(1, a1);

    ISSUE_A(a1, At, 3);
    asm volatile("s_waitcnt lgkmcnt(4)" ::: "memory");
    __builtin_amdgcn_sched_barrier(0);
    MFMA_PH(2, a0);

    asm volatile("s_waitcnt lgkmcnt(0)" ::: "memory");
    __builtin_amdgcn_sched_barrier(0);
    MFMA_PH(3, a1);

    if (kt < 15) {
      // g[] (tile kt+1) has had a full tile of latency; cvt + write to the
      // buffer all waves finished reading at the END of tile kt-1.
      asm volatile("s_waitcnt vmcnt(0)" ::: "memory");
      __builtin_amdgcn_sched_barrier(0);
      CVT_WRITE((kt & 1) ^ 1);
      if (kt < 14) LOADG(kt + 2);               // next stage, full-tile window
      asm volatile("s_waitcnt lgkmcnt(0)" ::: "memory");  // ds_writes done
      __builtin_amdgcn_sched_barrier(0);
    }
    __builtin_amdgcn_s_barrier();               // tile seam (1 barrier/tile)
  }
#undef MFMA_PH
#undef LOAD_B
#undef ISSUE_A

  // ---- per-row inv-norm: reduce sumsq across the 8 threads sharing a row ----
#pragma unroll
  for (int off = 4; off >= 1; off >>= 1) {
    ss0 += __shfl_xor(ss0, off);
    ss1 += __shfl_xor(ss1, off);
    ss2 += __shfl_xor(ss2, off);
    ss3 += __shfl_xor(ss3, off);
  }
  if ((lane & 7) == 0) {
    invnLDS[r0 +  0] = (ss0 > 0.f) ? (1.f / sqrtf(ss0)) : 0.f;
    invnLDS[r0 + 32] = (ss1 > 0.f) ? (1.f / sqrtf(ss1)) : 0.f;
    invnLDS[r0 + 64] = (ss2 > 0.f) ? (1.f / sqrtf(ss2)) : 0.f;
    invnLDS[r0 + 96] = (ss3 > 0.f) ? (1.f / sqrtf(ss3)) : 0.f;
  }
  __syncthreads();

  // epilogue: C/D layout col=lane&15, row=(lane>>4)*4+reg; scale by invn[row]
  float* outB = out + ((size_t)b * NS + m0) * ND + n0;
#pragma unroll
  for (int i = 0; i < 8; ++i) {
    f32x4 iv = *(const f32x4*)&invnLDS[i * 16 + q * 4];
#pragma unroll
    for (int rg = 0; rg < 4; ++rg) {
      int r = i * 16 + q * 4 + rg;
      float* orow = outB + (size_t)r * ND + wn * 64 + l16;
#pragma unroll
      for (int n = 0; n < 4; ++n)
        orow[n * 16] = acc[i][n][rg] * iv[rg];
    }
  }
#undef CVT_WRITE
#undef LOADG
}

// ---------- small-ws fallback (round-1 kernels) ----------
__global__ void enorm_kernel(const float* __restrict__ emb,
                             float* __restrict__ inv_norm) {
  int wave = threadIdx.x >> 6;
  int lane = threadIdx.x & 63;
  int row = blockIdx.x * 4 + wave;
  const float4* p = (const float4*)(emb + (size_t)row * ND);
  float s = 0.f;
#pragma unroll
  for (int j = 0; j < 4; ++j) {
    float4 v = p[lane + 64 * j];
    s += v.x * v.x + v.y * v.y + v.z * v.z + v.w * v.w;
  }
#pragma unroll
  for (int off = 32; off >= 1; off >>= 1) s += __shfl_down(s, off);
  if (lane == 0) inv_norm[row] = (s > 0.f) ? (1.f / sqrtf(s)) : 0.f;
}

__global__ __launch_bounds__(256)
void corr_gemm_kernel(const float* __restrict__ emb,
                      const float* __restrict__ inv_norm,
                      const unsigned short* __restrict__ a_n,
                      float* __restrict__ out) {
  __shared__ unsigned short copies[8][2056];
  __shared__ unsigned short Atile[128][40];

  const int nt = blockIdx.x, mt = blockIdx.y, b = blockIdx.z;
  const int n0 = nt * 128, m0 = mt * 128;
  const int t = threadIdx.x;

  {
    const unsigned short* an = a_n + (size_t)b * ND;
    int p = t & 7;
    int x0 = (t >> 3) * 64;
#pragma unroll
    for (int j = 0; j < 64; j += 4) {
      ushort4 u;
      u.x = an[(x0 + j + 0 + p) & 1023];
      u.y = an[(x0 + j + 1 + p) & 1023];
      u.z = an[(x0 + j + 2 + p) & 1023];
      u.w = an[(x0 + j + 3 + p) & 1023];
      *(ushort4*)&copies[p][x0 + j] = u;
    }
  }

  const int ar = t >> 3;
  const int ac = (t & 7) * 4;
  float invn[4];
#pragma unroll
  for (int w = 0; w < 4; ++w)
    invn[w] = inv_norm[b * NS + m0 + ar + 32 * w];

  const int lane = t & 63;
  const int wv = t >> 6;
  const int wm = wv >> 1, wn = wv & 1;
  const int q = lane >> 4, l16 = lane & 15;

  f32x4 acc[4][4];
#pragma unroll
  for (int i = 0; i < 4; ++i)
#pragma unroll
    for (int j = 0; j < 4; ++j)
      acc[i][j] = (f32x4){0.f, 0.f, 0.f, 0.f};

  const float* embB = emb + ((size_t)b * NS + m0) * ND;

  for (int k0 = 0; k0 < ND; k0 += 32) {
    __syncthreads();
#pragma unroll
    for (int w = 0; w < 4; ++w) {
      int r = ar + 32 * w;
      float4 v = *(const float4*)(embB + (size_t)r * ND + k0 + ac);
      float in = invn[w];
      ushort4 u;
      u.x = f2bf(v.x * in); u.y = f2bf(v.y * in);
      u.z = f2bf(v.z * in); u.w = f2bf(v.w * in);
      *(ushort4*)&Atile[r][ac] = u;
    }
    __syncthreads();

    bf16x8 af[4], bfr[4];
#pragma unroll
    for (int r = 0; r < 4; ++r) {
      int m = wm * 64 + r * 16 + l16;
      af[r] = *(const bf16x8*)&Atile[m][q * 8];
    }
#pragma unroll
    for (int r = 0; r < 4; ++r) {
      int ng = n0 + wn * 64 + r * 16 + l16;
      int e0 = k0 + 8 * q - ng + 1024;
      int p = e0 & 7;
      bfr[r] = *(const bf16x8*)&copies[p][e0 - p];
    }
#pragma unroll
    for (int i = 0; i < 4; ++i)
#pragma unroll
      for (int j = 0; j < 4; ++j)
        acc[i][j] = __builtin_amdgcn_mfma_f32_16x16x32_bf16(af[i], bfr[j], acc[i][j], 0, 0, 0);
  }

  float* outB = out + ((size_t)b * NS + m0) * ND + n0;
#pragma unroll
  for (int i = 0; i < 4; ++i) {
#pragma unroll
    for (int rg = 0; rg < 4; ++rg) {
      int s = wm * 64 + i * 16 + q * 4 + rg;
      float* orow = outB + (size_t)s * ND + wn * 64 + l16;
#pragma unroll
      for (int j = 0; j < 4; ++j)
        orow[j * 16] = acc[i][j][rg];
    }
  }
}

extern "C" void kernel_launch(void* const* d_in, const int* in_sizes, int n_in,
                              void* d_out, int out_size, void* d_ws, size_t ws_size,
                              hipStream_t stream) {
  const float* emb = (const float*)d_in[0];
  const float* aspect = (const float*)d_in[1];
  float* out = (float*)d_out;

  if (ws_size >= 65536) {
    unsigned short* a_n = (unsigned short*)d_ws;
    anorm_kernel<<<NB, 256, 0, stream>>>(aspect, a_n);
    // grid (b, mt, nt): flat = b + 32*(mt + 4*nt) -> XCD = b%8; all 16 tiles
    // of batch b share an XCD -> emb panel + a_n L2 reuse across siblings.
    corr_gemm11_kernel<<<dim3(NB, 4, 4), 256, 0, stream>>>(emb, a_n, out);
  } else {
    float* inv_norm = (float*)d_ws;
    unsigned short* a_n = (unsigned short*)((char*)d_ws + 65536);
    enorm_kernel<<<4096, 256, 0, stream>>>(emb, inv_norm);
    anorm_kernel<<<NB, 256, 0, stream>>>(aspect, a_n);
    corr_gemm_kernel<<<dim3(8, 4, NB), 256, 0, stream>>>(emb, inv_norm, a_n, out);
  }
}